// Round 9
// baseline (71.206 us; speedup 1.0000x reference)
//
#include <hip/hip_runtime.h>

#define TT 1024
#define LL 64
#define SEG 32             // time-steps per wave segment
#define WARM 8             // warm-up: worst-case 0.462^7 ~ 5e-3 nats/junction
#define NW 16              // waves per block
#define NBLK 2             // blocks per sequence
#define LOG2E 1.44269504088896340736f
#define LN2   0.69314718055994530942f

typedef __fp16 half2v __attribute__((ext_vector_type(2)));
__device__ __forceinline__ half2v int_as_h2(int x) { union { int i; half2v h; } u; u.i = x; return u.h; }
__device__ __forceinline__ int h2_as_int(half2v x) { union { int i; half2v h; } u; u.h = x; return u.i; }

// 2 blocks x 16 waves per sequence; wave (h,w) owns segment s = 16h+w of 32,
// i.e. t in [1+32s, 1+32(s+1)) clamped by slen, warm-started WARM steps
// earlier (positive transfer operator: Hilbert diameter of E=exp(trans) <= 2
// -> contraction <= tanh(0.5)=0.462/step). delta_s = A(u@hi)-A(u@lo)
// telescopes to log_norm; segment 0 exact from t=0. 2 blocks/CU = 8 waves/SIMD
// so dependency-chain stalls of one wave hide under another's issue.
//
// Step, one column per lane: lane j holds u_j (f32), E-pairs ej[m] f16x2.
//   v_j = (sum_m pair_m(u) . ej[m]) * exp(logit[t][j])
//   renorm by exact pow-2 of v_0 (readfirstlane exponent), C += e
//   repack pairs via 2 ds_bpermute + cvt_pkrtz
// Logit rows in an 8-slot named register ring (true distance-8 prefetch).

__global__ __launch_bounds__(1024) void crf_fwd_kernel(
    const float* __restrict__ logits,    // [B][T][L]
    const int*   __restrict__ labels,    // [B][T]
    const int*   __restrict__ seq_lens,  // [B]
    const float* __restrict__ trans,     // [L][L]
    float*       __restrict__ part)      // [B*NBLK]
{
    const int g    = blockIdx.x;
    const int b    = g >> 1;
    const int h    = g & 1;
    const int tid  = threadIdx.x;
    const int lane = tid & 63;
    const int w    = tid >> 6;
    const int s    = NW * h + w;         // segment index 0..31
    const int slen = seq_lens[b];
    const float* lg  = logits + (size_t)b * TT * LL;
    const int*   lab = labels + b * TT;

    __shared__ float ssc[NW];
    __shared__ float sdelta[NW];

    // ---- Phase A: path score (unary + binary), h==0 block only ----
    float sc = 0.f;
    if (h == 0) {
        for (int t = tid; t < slen; t += 1024) {
            int l1 = lab[t];
            sc += lg[(size_t)t * LL + l1];
            if (t >= 1) sc += trans[lab[t - 1] * LL + l1];
        }
        #pragma unroll
        for (int off = 32; off; off >>= 1) sc += __shfl_xor(sc, off, 64);
    }
    if (lane == 0) ssc[w] = sc;

    const int lo = 1 + SEG * s;
    const int hi = (lo + SEG < slen) ? (lo + SEG) : slen;
    const bool active = (s == 0) || (lo < slen);

    float delta = 0.f;
    if (active) {
        const int start = (s == 0) ? 1 : (lo - WARM);   // >= 25 for s>=1
        const int lo1   = (s == 0) ? -1 : (lo - 1);     // A_in measure point

        // E-column pairs for this lane's column j = lane
        int ej[32];
        #pragma unroll
        for (int m = 0; m < 32; ++m) {
            half2v pp;
            pp[0] = (__fp16)__builtin_amdgcn_exp2f(trans[(2 * m)     * LL + lane] * LOG2E);
            pp[1] = (__fp16)__builtin_amdgcn_exp2f(trans[(2 * m + 1) * LL + lane] * LOG2E);
            ej[m] = h2_as_int(pp);
        }

        const float* col = lg + lane;
        const int pad0 = (lane & 31) << 3;     // bpermute byte addr of lane 2k
        const int pad1 = pad0 + 4;             // lane 2k+1

        int C = 0;
        float u;
        int upk;

#define RENORM(V) { \
    int ebits = (__builtin_amdgcn_readfirstlane(__float_as_int(V)) >> 23) & 0xFF; \
    C += ebits - 127; \
    float scl = __int_as_float((254 - ebits) << 23); \
    u = (V) * scl; \
}
#define PACK() { \
    int pa_ = __builtin_amdgcn_ds_bpermute(pad0, __float_as_int(u)); \
    int pb_ = __builtin_amdgcn_ds_bpermute(pad1, __float_as_int(u)); \
    upk = h2_as_int(__builtin_amdgcn_cvt_pkrtz(__int_as_float(pa_), __int_as_float(pb_))); \
}
#define MEASURE(OUT) { \
    float us_ = u; \
    _Pragma("unroll") \
    for (int off = 32; off; off >>= 1) us_ += __shfl_xor(us_, off, 64); \
    OUT = ((float)C + __builtin_amdgcn_logf(us_)) * LN2; \
}

        // init u from row start-1 (exact for s==0: row 0)
        {
            float v0 = __builtin_amdgcn_exp2f(col[(size_t)(start - 1) * LL] * LOG2E);
            RENORM(v0);
            PACK();
        }

        float A_in = 0.f, A_out;

        // ring preload: rows start .. start+7 (start+7 <= 999 < TT)
        float fR0 = col[(size_t)(start + 0) * LL];
        float fR1 = col[(size_t)(start + 1) * LL];
        float fR2 = col[(size_t)(start + 2) * LL];
        float fR3 = col[(size_t)(start + 3) * LL];
        float fR4 = col[(size_t)(start + 4) * LL];
        float fR5 = col[(size_t)(start + 5) * LL];
        float fR6 = col[(size_t)(start + 6) * LL];
        float fR7 = col[(size_t)(start + 7) * LL];

#define RSTEP(I) do { \
    if (t < hi) { \
        float g_ = __builtin_amdgcn_exp2f(fR##I * LOG2E); \
        int nr_ = t + 8; nr_ = nr_ < TT ? nr_ : TT - 1; \
        fR##I = col[(size_t)nr_ * LL];   /* slot reloaded; next read 8 steps away */ \
        float a1 = 0.f, a2 = 0.f, a3 = 0.f, a4 = 0.f; \
        _Pragma("unroll") \
        for (int m = 0; m < 32; m += 4) { \
            int q0 = __builtin_amdgcn_readlane(upk, m); \
            int q1 = __builtin_amdgcn_readlane(upk, m + 1); \
            int q2 = __builtin_amdgcn_readlane(upk, m + 2); \
            int q3 = __builtin_amdgcn_readlane(upk, m + 3); \
            a1 = __builtin_amdgcn_fdot2(int_as_h2(q0), int_as_h2(ej[m]),     a1, false); \
            a2 = __builtin_amdgcn_fdot2(int_as_h2(q1), int_as_h2(ej[m + 1]), a2, false); \
            a3 = __builtin_amdgcn_fdot2(int_as_h2(q2), int_as_h2(ej[m + 2]), a3, false); \
            a4 = __builtin_amdgcn_fdot2(int_as_h2(q3), int_as_h2(ej[m + 3]), a4, false); \
        } \
        float v_ = ((a1 + a2) + (a3 + a4)) * g_; \
        RENORM(v_); \
        PACK(); \
        if (t == lo1) MEASURE(A_in); \
        ++t; \
    } \
} while (0)

        int t = start;
        while (t < hi) {
            RSTEP(0); RSTEP(1); RSTEP(2); RSTEP(3);
            RSTEP(4); RSTEP(5); RSTEP(6); RSTEP(7);
        }

        MEASURE(A_out);
        delta = A_out - A_in;
    }

    if (lane == 0) sdelta[w] = delta;
    __syncthreads();

    if (tid == 0) {
        float sct = 0.f, dt = 0.f;
        #pragma unroll
        for (int i = 0; i < NW; ++i) { sct += ssc[i]; dt += sdelta[i]; }
        part[g] = dt - sct;   // partial (log_norm - path_score) contribution
    }
}

__global__ __launch_bounds__(512) void reduce_kernel(
    const float* __restrict__ part, float* __restrict__ out)
{
    int tid = threadIdx.x;
    float v = part[tid];
    #pragma unroll
    for (int off = 32; off; off >>= 1) v += __shfl_xor(v, off, 64);
    __shared__ float r[8];
    if ((tid & 63) == 0) r[tid >> 6] = v;
    __syncthreads();
    if (tid == 0) {
        float s = 0.f;
        #pragma unroll
        for (int i = 0; i < 8; ++i) s += r[i];
        out[0] = s;
    }
}

extern "C" void kernel_launch(void* const* d_in, const int* in_sizes, int n_in,
                              void* d_out, int out_size, void* d_ws, size_t ws_size,
                              hipStream_t stream) {
    const float* logits   = (const float*)d_in[0];
    const int*   labels   = (const int*)d_in[1];
    const int*   seq_lens = (const int*)d_in[2];
    const float* trans    = (const float*)d_in[3];
    float* part = (float*)d_ws;   // 512 floats of scratch

    crf_fwd_kernel<<<512, 1024, 0, stream>>>(logits, labels, seq_lens, trans, part);
    reduce_kernel<<<1, 512, 0, stream>>>(part, (float*)d_out);
}

// Round 10
// 63.786 us; speedup vs baseline: 1.1163x; 1.1163x over previous
//
#include <hip/hip_runtime.h>

#define TT 1024
#define LL 64
#define SEG 32             // time-steps per segment
#define NSEG 32            // segments per sequence (SEG*NSEG >= TT)
#define WARM 8             // warm-up: contraction <= 0.462/step -> ~5e-3 nats worst
#define LOG2E 1.44269504088896340736f
#define LN2   0.69314718055994530942f

typedef __fp16 half2v __attribute__((ext_vector_type(2)));
__device__ __forceinline__ half2v int_as_h2(int x) { union { int i; half2v h; } u; u.i = x; return u.h; }
__device__ __forceinline__ int h2_as_int(half2v x) { union { int i; half2v h; } u; u.h = x; return u.i; }

// FLAT SEGMENT GRID: 8192 independent waves (256 seq x 32 segments), packed
// 4 waves per 256-thread block, no LDS, no barriers. Wave wid handles
// (b,s) = (wid>>5, wid&31): t in [1+32s, 1+32(s+1)) clamped by slen,
// warm-started WARM steps earlier (positive transfer operator: Hilbert
// diameter of E=exp(trans) <= 2 -> contraction <= tanh(0.5)=0.462/step).
// delta_s = A(u@hi)-A(u@lo) telescopes to log_norm (segment 0 exact from
// t=0). Inactive waves write 0 and exit immediately -> uniform load across
// CUs (fixes the one-sequence-per-block imbalance tail of rounds 8/9).
// Each wave also scores its own t-range (unary+binary), so the path score
// needs no separate phase; part[wid] = delta_s - sc_s, reduced at the end.
//
// Step, one column per lane: lane j holds u_j (f32), E-pairs ej[m] f16x2.
//   v_j = (sum_m pair_m(u) . ej[m]) * exp(logit[t][j])
//   renorm by exact pow-2 of v_0 (readfirstlane exponent), C += e
//   repack pairs via 2 ds_bpermute + cvt_pkrtz
// Logit rows in an 8-slot named register ring (true distance-8 prefetch).

__global__ __launch_bounds__(256) void crf_seg_kernel(
    const float* __restrict__ logits,    // [B][T][L]
    const int*   __restrict__ labels,    // [B][T]
    const int*   __restrict__ seq_lens,  // [B]
    const float* __restrict__ trans,     // [L][L]
    float*       __restrict__ part)      // [B*NSEG]
{
    const int wid  = blockIdx.x * 4 + (threadIdx.x >> 6);
    const int b    = wid >> 5;
    const int s    = wid & (NSEG - 1);
    const int lane = threadIdx.x & 63;
    const int slen = seq_lens[b];
    const float* lg  = logits + (size_t)b * TT * LL;
    const int*   lab = labels + b * TT;

    const int lo = 1 + SEG * s;
    const int hi = (lo + SEG < slen) ? (lo + SEG) : slen;
    const bool active = (s == 0) || (lo < slen);

    float result = 0.f;
    if (active) {
        // ---- path-score portion for this segment's t-range ----
        float sc = 0.f;
        {
            int t0 = lo + lane;              // lane < SEG covers lo..hi-1
            if (lane < SEG && t0 < hi) {
                int l1 = lab[t0];
                sc = lg[(size_t)t0 * LL + l1] + trans[lab[t0 - 1] * LL + l1];
            }
            if (s == 0 && lane == 0) sc += lg[lab[0]];   // t = 0 unary
            #pragma unroll
            for (int off = 32; off; off >>= 1) sc += __shfl_xor(sc, off, 64);
        }

        const int start = (s == 0) ? 1 : (lo - WARM);    // >= 25 for s>=1
        const int lo1   = (s == 0) ? -1 : (lo - 1);      // A_in measure point

        // E-column pairs for this lane's column j = lane
        int ej[32];
        #pragma unroll
        for (int m = 0; m < 32; ++m) {
            half2v pp;
            pp[0] = (__fp16)__builtin_amdgcn_exp2f(trans[(2 * m)     * LL + lane] * LOG2E);
            pp[1] = (__fp16)__builtin_amdgcn_exp2f(trans[(2 * m + 1) * LL + lane] * LOG2E);
            ej[m] = h2_as_int(pp);
        }

        const float* col = lg + lane;
        const int pad0 = (lane & 31) << 3;     // bpermute byte addr of lane 2k
        const int pad1 = pad0 + 4;             // lane 2k+1

        int C = 0;
        float u;
        int upk;

#define RENORM(V) { \
    int ebits = (__builtin_amdgcn_readfirstlane(__float_as_int(V)) >> 23) & 0xFF; \
    C += ebits - 127; \
    float scl = __int_as_float((254 - ebits) << 23); \
    u = (V) * scl; \
}
#define PACK() { \
    int pa_ = __builtin_amdgcn_ds_bpermute(pad0, __float_as_int(u)); \
    int pb_ = __builtin_amdgcn_ds_bpermute(pad1, __float_as_int(u)); \
    upk = h2_as_int(__builtin_amdgcn_cvt_pkrtz(__int_as_float(pa_), __int_as_float(pb_))); \
}
#define MEASURE(OUT) { \
    float us_ = u; \
    _Pragma("unroll") \
    for (int off = 32; off; off >>= 1) us_ += __shfl_xor(us_, off, 64); \
    OUT = ((float)C + __builtin_amdgcn_logf(us_)) * LN2; \
}

        // init u from row start-1 (exact for s==0: row 0)
        {
            float v0 = __builtin_amdgcn_exp2f(col[(size_t)(start - 1) * LL] * LOG2E);
            RENORM(v0);
            PACK();
        }

        float A_in = 0.f, A_out;

        // ring preload: rows start .. start+7 (always < TT)
        float fR0 = col[(size_t)(start + 0) * LL];
        float fR1 = col[(size_t)(start + 1) * LL];
        float fR2 = col[(size_t)(start + 2) * LL];
        float fR3 = col[(size_t)(start + 3) * LL];
        float fR4 = col[(size_t)(start + 4) * LL];
        float fR5 = col[(size_t)(start + 5) * LL];
        float fR6 = col[(size_t)(start + 6) * LL];
        float fR7 = col[(size_t)(start + 7) * LL];

#define RSTEP(I) do { \
    if (t < hi) { \
        float g_ = __builtin_amdgcn_exp2f(fR##I * LOG2E); \
        int nr_ = t + 8; nr_ = nr_ < TT ? nr_ : TT - 1; \
        fR##I = col[(size_t)nr_ * LL];   /* slot reloaded; next read 8 steps away */ \
        float a1 = 0.f, a2 = 0.f, a3 = 0.f, a4 = 0.f; \
        _Pragma("unroll") \
        for (int m = 0; m < 32; m += 4) { \
            int q0 = __builtin_amdgcn_readlane(upk, m); \
            int q1 = __builtin_amdgcn_readlane(upk, m + 1); \
            int q2 = __builtin_amdgcn_readlane(upk, m + 2); \
            int q3 = __builtin_amdgcn_readlane(upk, m + 3); \
            a1 = __builtin_amdgcn_fdot2(int_as_h2(q0), int_as_h2(ej[m]),     a1, false); \
            a2 = __builtin_amdgcn_fdot2(int_as_h2(q1), int_as_h2(ej[m + 1]), a2, false); \
            a3 = __builtin_amdgcn_fdot2(int_as_h2(q2), int_as_h2(ej[m + 2]), a3, false); \
            a4 = __builtin_amdgcn_fdot2(int_as_h2(q3), int_as_h2(ej[m + 3]), a4, false); \
        } \
        float v_ = ((a1 + a2) + (a3 + a4)) * g_; \
        RENORM(v_); \
        PACK(); \
        if (t == lo1) MEASURE(A_in); \
        ++t; \
    } \
} while (0)

        int t = start;
        while (t < hi) {
            RSTEP(0); RSTEP(1); RSTEP(2); RSTEP(3);
            RSTEP(4); RSTEP(5); RSTEP(6); RSTEP(7);
        }

        MEASURE(A_out);
        result = (A_out - A_in) - sc;
    }

    if (lane == 0) part[wid] = result;
}

__global__ __launch_bounds__(1024) void reduce_kernel(
    const float* __restrict__ part, float* __restrict__ out)
{
    int tid = threadIdx.x;
    float v = 0.f;
    #pragma unroll
    for (int i = 0; i < 8; ++i) v += part[tid + 1024 * i];
    #pragma unroll
    for (int off = 32; off; off >>= 1) v += __shfl_xor(v, off, 64);
    __shared__ float r[16];
    if ((tid & 63) == 0) r[tid >> 6] = v;
    __syncthreads();
    if (tid == 0) {
        float s = 0.f;
        #pragma unroll
        for (int i = 0; i < 16; ++i) s += r[i];
        out[0] = s;
    }
}

extern "C" void kernel_launch(void* const* d_in, const int* in_sizes, int n_in,
                              void* d_out, int out_size, void* d_ws, size_t ws_size,
                              hipStream_t stream) {
    const float* logits   = (const float*)d_in[0];
    const int*   labels   = (const int*)d_in[1];
    const int*   seq_lens = (const int*)d_in[2];
    const float* trans    = (const float*)d_in[3];
    float* part = (float*)d_ws;   // 8192 floats (32 KB) of scratch

    crf_seg_kernel<<<2048, 256, 0, stream>>>(logits, labels, seq_lens, trans, part);
    reduce_kernel<<<1, 1024, 0, stream>>>(part, (float*)d_out);
}

// Round 11
// 56.847 us; speedup vs baseline: 1.2526x; 1.1221x over previous
//
#include <hip/hip_runtime.h>

#define TT 1024
#define LL 64
#define BB 256             // batch
#define SEG 32             // time-steps per segment
#define NSEG 32            // segments per sequence (SEG*NSEG >= TT)
#define WARM 8             // warm-up: contraction <= 0.462/step -> ~5e-3 nats worst
#define LOG2E 1.44269504088896340736f
#define LN2   0.69314718055994530942f

typedef __fp16 half2v __attribute__((ext_vector_type(2)));
__device__ __forceinline__ half2v int_as_h2(int x) { union { int i; half2v h; } u; u.i = x; return u.h; }
__device__ __forceinline__ int h2_as_int(half2v x) { union { int i; half2v h; } u; u.h = x; return u.i; }

// FLAT SEGMENT GRID, TRANSPOSED MAP: 8192 independent waves (256 seq x 32
// segments), 4 waves per 256-thread block, no LDS, no barriers.
//   b = wid & 255, s = wid >> 8        (TRANSPOSED vs round 10!)
// Round 10's map (b=wid>>5) gave every CU the SAME segment window each
// dispatch round -> CUs owning segments 28-31 idle 88% of the time while
// segment-0-3 CUs did 8x the work. Transposed, CU c's 8 resident blocks
// span segment windows {c>>6, +4, ..., +28} -> per-CU active load ~= global
// mean for any seq_lens draw.
// Wave (b,s): t in [1+32s, 1+32(s+1)) clamped by slen, warm-started WARM
// steps earlier (positive transfer operator: Hilbert diameter of
// E=exp(trans) <= 2 -> contraction <= tanh(0.5)=0.462/step).
// delta_s = A(u@hi)-A(u@lo) telescopes to log_norm (segment 0 exact from
// t=0). Each wave scores its own t-range; part[wid] = delta_s - sc_s.
//
// Step, one column per lane: lane j holds u_j (f32), E-pairs ej[m] f16x2.
//   v_j = (sum_m pair_m(u) . ej[m]) * exp(logit[t][j])
//   renorm by exact pow-2 of v_0 (readfirstlane exponent), C += e
//   repack pairs via 2 ds_bpermute + cvt_pkrtz
// Logit rows in an 8-slot named register ring (true distance-8 prefetch).

__global__ __launch_bounds__(256) void crf_seg_kernel(
    const float* __restrict__ logits,    // [B][T][L]
    const int*   __restrict__ labels,    // [B][T]
    const int*   __restrict__ seq_lens,  // [B]
    const float* __restrict__ trans,     // [L][L]
    float*       __restrict__ part)      // [B*NSEG]
{
    const int wid  = blockIdx.x * 4 + (threadIdx.x >> 6);
    const int b    = wid & (BB - 1);     // TRANSPOSED: sequence = low bits
    const int s    = wid >> 8;           //             segment  = high bits
    const int lane = threadIdx.x & 63;
    const int slen = seq_lens[b];
    const float* lg  = logits + (size_t)b * TT * LL;
    const int*   lab = labels + b * TT;

    const int lo = 1 + SEG * s;
    const int hi = (lo + SEG < slen) ? (lo + SEG) : slen;
    const bool active = (s == 0) || (lo < slen);

    float result = 0.f;
    if (active) {
        // ---- path-score portion for this segment's t-range ----
        float sc = 0.f;
        {
            int t0 = lo + lane;              // lane < SEG covers lo..hi-1
            if (lane < SEG && t0 < hi) {
                int l1 = lab[t0];
                sc = lg[(size_t)t0 * LL + l1] + trans[lab[t0 - 1] * LL + l1];
            }
            if (s == 0 && lane == 0) sc += lg[lab[0]];   // t = 0 unary
            #pragma unroll
            for (int off = 32; off; off >>= 1) sc += __shfl_xor(sc, off, 64);
        }

        const int start = (s == 0) ? 1 : (lo - WARM);    // >= 25 for s>=1
        const int lo1   = (s == 0) ? -1 : (lo - 1);      // A_in measure point

        // E-column pairs for this lane's column j = lane
        int ej[32];
        #pragma unroll
        for (int m = 0; m < 32; ++m) {
            half2v pp;
            pp[0] = (__fp16)__builtin_amdgcn_exp2f(trans[(2 * m)     * LL + lane] * LOG2E);
            pp[1] = (__fp16)__builtin_amdgcn_exp2f(trans[(2 * m + 1) * LL + lane] * LOG2E);
            ej[m] = h2_as_int(pp);
        }

        const float* col = lg + lane;
        const int pad0 = (lane & 31) << 3;     // bpermute byte addr of lane 2k
        const int pad1 = pad0 + 4;             // lane 2k+1

        int C = 0;
        float u;
        int upk;

#define RENORM(V) { \
    int ebits = (__builtin_amdgcn_readfirstlane(__float_as_int(V)) >> 23) & 0xFF; \
    C += ebits - 127; \
    float scl = __int_as_float((254 - ebits) << 23); \
    u = (V) * scl; \
}
#define PACK() { \
    int pa_ = __builtin_amdgcn_ds_bpermute(pad0, __float_as_int(u)); \
    int pb_ = __builtin_amdgcn_ds_bpermute(pad1, __float_as_int(u)); \
    upk = h2_as_int(__builtin_amdgcn_cvt_pkrtz(__int_as_float(pa_), __int_as_float(pb_))); \
}
#define MEASURE(OUT) { \
    float us_ = u; \
    _Pragma("unroll") \
    for (int off = 32; off; off >>= 1) us_ += __shfl_xor(us_, off, 64); \
    OUT = ((float)C + __builtin_amdgcn_logf(us_)) * LN2; \
}

        // init u from row start-1 (exact for s==0: row 0)
        {
            float v0 = __builtin_amdgcn_exp2f(col[(size_t)(start - 1) * LL] * LOG2E);
            RENORM(v0);
            PACK();
        }

        float A_in = 0.f, A_out;

        // ring preload: rows start .. start+7 (always < TT)
        float fR0 = col[(size_t)(start + 0) * LL];
        float fR1 = col[(size_t)(start + 1) * LL];
        float fR2 = col[(size_t)(start + 2) * LL];
        float fR3 = col[(size_t)(start + 3) * LL];
        float fR4 = col[(size_t)(start + 4) * LL];
        float fR5 = col[(size_t)(start + 5) * LL];
        float fR6 = col[(size_t)(start + 6) * LL];
        float fR7 = col[(size_t)(start + 7) * LL];

#define RSTEP(I) do { \
    if (t < hi) { \
        float g_ = __builtin_amdgcn_exp2f(fR##I * LOG2E); \
        int nr_ = t + 8; nr_ = nr_ < TT ? nr_ : TT - 1; \
        fR##I = col[(size_t)nr_ * LL];   /* slot reloaded; next read 8 steps away */ \
        float a1 = 0.f, a2 = 0.f, a3 = 0.f, a4 = 0.f; \
        _Pragma("unroll") \
        for (int m = 0; m < 32; m += 4) { \
            int q0 = __builtin_amdgcn_readlane(upk, m); \
            int q1 = __builtin_amdgcn_readlane(upk, m + 1); \
            int q2 = __builtin_amdgcn_readlane(upk, m + 2); \
            int q3 = __builtin_amdgcn_readlane(upk, m + 3); \
            a1 = __builtin_amdgcn_fdot2(int_as_h2(q0), int_as_h2(ej[m]),     a1, false); \
            a2 = __builtin_amdgcn_fdot2(int_as_h2(q1), int_as_h2(ej[m + 1]), a2, false); \
            a3 = __builtin_amdgcn_fdot2(int_as_h2(q2), int_as_h2(ej[m + 2]), a3, false); \
            a4 = __builtin_amdgcn_fdot2(int_as_h2(q3), int_as_h2(ej[m + 3]), a4, false); \
        } \
        float v_ = ((a1 + a2) + (a3 + a4)) * g_; \
        RENORM(v_); \
        PACK(); \
        if (t == lo1) MEASURE(A_in); \
        ++t; \
    } \
} while (0)

        int t = start;
        while (t < hi) {
            RSTEP(0); RSTEP(1); RSTEP(2); RSTEP(3);
            RSTEP(4); RSTEP(5); RSTEP(6); RSTEP(7);
        }

        MEASURE(A_out);
        result = (A_out - A_in) - sc;
    }

    if (lane == 0) part[wid] = result;
}

__global__ __launch_bounds__(1024) void reduce_kernel(
    const float* __restrict__ part, float* __restrict__ out)
{
    int tid = threadIdx.x;
    float v = 0.f;
    #pragma unroll
    for (int i = 0; i < 8; ++i) v += part[tid + 1024 * i];
    #pragma unroll
    for (int off = 32; off; off >>= 1) v += __shfl_xor(v, off, 64);
    __shared__ float r[16];
    if ((tid & 63) == 0) r[tid >> 6] = v;
    __syncthreads();
    if (tid == 0) {
        float s = 0.f;
        #pragma unroll
        for (int i = 0; i < 16; ++i) s += r[i];
        out[0] = s;
    }
}

extern "C" void kernel_launch(void* const* d_in, const int* in_sizes, int n_in,
                              void* d_out, int out_size, void* d_ws, size_t ws_size,
                              hipStream_t stream) {
    const float* logits   = (const float*)d_in[0];
    const int*   labels   = (const int*)d_in[1];
    const int*   seq_lens = (const int*)d_in[2];
    const float* trans    = (const float*)d_in[3];
    float* part = (float*)d_ws;   // 8192 floats (32 KB) of scratch

    crf_seg_kernel<<<2048, 256, 0, stream>>>(logits, labels, seq_lens, trans, part);
    reduce_kernel<<<1, 1024, 0, stream>>>(part, (float*)d_out);
}